// Round 13
// baseline (84.794 us; speedup 1.0000x reference)
//
#include <hip/hip_runtime.h>

#define N_ATOMS  4096
#define N_RBF    16
#define N_HIDDEN 64
#define NTHREADS 512
#define WPB      8                  // waves per block, 1 atom per wave
#define NBLOCKS  (N_ATOMS / WPB)    // 512
#define QCAP     288                // per-wave true-neighbor queue (max ~190; also 272 scratch for allreduce)
#define GRIDC    24                 // cells per axis, cell size 5.0, range +-60
#define NCELL    (GRIDC * GRIDC * GRIDC)   // 13824
#define CCAP     96                 // atoms per cell cap (central-cell mean ~45, +7 sigma)
#define CELL_INV 0.2f               // 1/5.0
#define RANGEF   60.0f

// ---- node 1: zero the cell counters (ws is poisoned 0xAA every launch) ----
__global__ __launch_bounds__(256) void zero_counts(int* __restrict__ count) {
    const int i = blockIdx.x * 256 + threadIdx.x;
    if (i < NCELL) count[i] = 0;
}

// ---- node 2: bin atoms into cells (positions copied into slots) ----
__global__ __launch_bounds__(256) void bin_kernel(const float* __restrict__ pos,
                                                  int* __restrict__ count,
                                                  float4* __restrict__ cellAtoms) {
    const int i = blockIdx.x * 256 + threadIdx.x;
    if (i >= N_ATOMS) return;
    const float x = pos[3 * i + 0], y = pos[3 * i + 1], z = pos[3 * i + 2];
    int cx = (int)floorf((x + RANGEF) * CELL_INV);
    int cy = (int)floorf((y + RANGEF) * CELL_INV);
    int cz = (int)floorf((z + RANGEF) * CELL_INV);
    cx = min(max(cx, 0), GRIDC - 1);   // monotone clamp preserves cell-adjacency
    cy = min(max(cy, 0), GRIDC - 1);   // of any pair within the 5.0 cutoff
    cz = min(max(cz, 0), GRIDC - 1);
    const int cell = cx + GRIDC * (cy + GRIDC * cz);
    int slot = atomicAdd(&count[cell], 1);
    if (slot >= CCAP) slot = CCAP - 1;   // ~+7sigma; effectively unreachable
    cellAtoms[cell * CCAP + slot] = make_float4(x, y, z, 0.0f);
}

// One pair's RBF contribution into f[0..15]. d2=1e8 sentinel -> exactly 0.
__device__ __forceinline__ void accum_rbf(float d2, float (&f)[N_RBF]) {
    const float d  = sqrtf(d2);
    const float sm = 0.5f + 0.5f * __cosf(0.62831853071795865f * d); // 0.5*(1+cos(pi*d/5))
    #pragma unroll
    for (int k = 0; k < N_RBF; ++k) {
        const float t = d - (0.5f + 0.3f * (float)k);   // centers 0.5+0.3k
        f[k] += sm * __expf(-20.48f * t * t);           // 1/(2*eta^2) = 20.48
    }
}

__device__ __forceinline__ int wave_prefix(unsigned long long m) {
    return __builtin_amdgcn_mbcnt_hi((unsigned)(m >> 32),
            __builtin_amdgcn_mbcnt_lo((unsigned)m, 0u));
}

// ---- node 3: per-atom candidates from 27 neighbor cells -> RBF -> MLP ----
__global__ __launch_bounds__(NTHREADS) void fused_sr_kernel(
    const float* __restrict__ pos,        // (N,3) - own-atom position (uniform)
    const int* __restrict__ count,        // (NCELL,)
    const float4* __restrict__ cellAtoms, // (NCELL, CCAP)
    const float* __restrict__ W1,         // (16,64)
    const float* __restrict__ b1,         // (64,)
    const float* __restrict__ W2,         // (64,64)
    const float* __restrict__ b2,         // (64,)
    const float* __restrict__ W3,         // (64,1)
    float* __restrict__ partial)          // NBLOCKS block partials
{
    __shared__ float qd[WPB][QCAP];                       // 9 KB d^2 queues / scratch
    __shared__ __align__(16) float h1buf[WPB][N_HIDDEN];  // 2 KB
    __shared__ float ered[WPB];

    const int tid  = threadIdx.x;
    const int lane = tid & 63;
    const int w    = tid >> 6;
    const int i    = blockIdx.x * WPB + w;   // this wave's atom

    // wave-uniform own position (same-address loads broadcast)
    const float xi = pos[3 * i + 0], yi = pos[3 * i + 1], zi = pos[3 * i + 2];
    int cx = (int)floorf((xi + RANGEF) * CELL_INV);
    int cy = (int)floorf((yi + RANGEF) * CELL_INV);
    int cz = (int)floorf((zi + RANGEF) * CELL_INV);
    cx = min(max(cx, 0), GRIDC - 1);
    cy = min(max(cy, 0), GRIDC - 1);
    cz = min(max(cz, 0), GRIDC - 1);

    // header round: lane l<27 owns neighbor offset (l%3-1, l/3%3-1, l/9-1)
    int myCell = 0, myCnt = 0;
    if (lane < 27) {
        const int nx = cx + (lane % 3) - 1;
        const int ny = cy + ((lane / 3) % 3) - 1;
        const int nz = cz + (lane / 9) - 1;
        if (nx >= 0 && nx < GRIDC && ny >= 0 && ny < GRIDC && nz >= 0 && nz < GRIDC) {
            myCell = nx + GRIDC * (ny + GRIDC * nz);
            myCnt  = min(count[myCell], CCAP);   // single parallel count round
        }
    }

    // sweep candidates: <=27 cells, ballot-compact true neighbors into queue
    int qn = 0;
    for (int j = 0; j < 27; ++j) {
        const int cnt = __shfl(myCnt, j, 64);    // readlane broadcast
        if (cnt == 0) continue;                  // wave-uniform skip
        const int cid = __shfl(myCell, j, 64);
        const float4* cbase = &cellAtoms[cid * CCAP];
        for (int b = 0; b < cnt; b += 64) {      // almost always one pass
            const int g = b + lane;
            float d2 = 1e8f;
            if (g < cnt) {
                const float4 pj = cbase[g];      // contiguous within cell
                const float dx = xi - pj.x, dy = yi - pj.y, dz = zi - pj.z;
                d2 = fmaf(dx, dx, fmaf(dy, dy, dz * dz));
            }
            const bool act = (d2 < 25.0f) && (d2 > 1e-12f);  // 1e-6 < d < 5
            const unsigned long long m = __ballot(act);
            if (m) {
                int widx = qn + wave_prefix(m);
                widx = widx < QCAP ? widx : QCAP - 1;
                if (act) qd[w][widx] = d2;
                qn += (int)__popcll(m);
            }
        }
    }

    // ---- drain: full-lane RBF evaluation (true neighbors only) ----
    float f[N_RBF];
    #pragma unroll
    for (int k = 0; k < N_RBF; ++k) f[k] = 0.0f;
    for (int b = 0; b < qn; b += 64) {
        const int g = b + lane;
        accum_rbf((g < qn) ? qd[w][g] : 1e8f, f);
    }

    // ---- allreduce of f[16]: 2 xor folds + LDS transpose finish ----
    #pragma unroll
    for (int k = 0; k < N_RBF; ++k) {
        f[k] += __shfl_xor(f[k], 32, 64);
        f[k] += __shfl_xor(f[k], 16, 64);   // lane l: sum over lanes {l&15 + 16r}
    }
    float* tb = &qd[w][0];   // 288-float wave-exclusive scratch (queue dead; needs 272)
    if (lane < 16) {
        #pragma unroll
        for (int j = 0; j < 16; ++j) tb[lane * 16 + j] = f[j];
    }
    const int kk = lane & 15, rep = lane >> 4;
    float F = 0.0f;
    #pragma unroll
    for (int v = 0; v < 4; ++v) F += tb[(4 * rep + v) * 16 + kk];
    F += __shfl_xor(F, 16, 64);
    F += __shfl_xor(F, 32, 64);            // full sum for k=lane&15
    if (lane < 16) tb[256 + lane] = F;

    // ---- MLP: lane <-> hidden unit; features from LDS broadcast ----
    float a1 = b1[lane];
    #pragma unroll
    for (int k = 0; k < N_RBF; ++k)
        a1 = fmaf(tb[256 + k], W1[k * N_HIDDEN + lane], a1);
    const float h1 = a1 / (1.0f + __expf(-a1));   // silu

    h1buf[w][lane] = h1;   // same-wave LDS exchange (DS in-order)
    float a2 = b2[lane];
    #pragma unroll
    for (int k = 0; k < N_HIDDEN; k += 4) {
        const float4 hv = *reinterpret_cast<const float4*>(&h1buf[w][k]);
        a2 = fmaf(hv.x, W2[(k + 0) * N_HIDDEN + lane], a2);
        a2 = fmaf(hv.y, W2[(k + 1) * N_HIDDEN + lane], a2);
        a2 = fmaf(hv.z, W2[(k + 2) * N_HIDDEN + lane], a2);
        a2 = fmaf(hv.w, W2[(k + 3) * N_HIDDEN + lane], a2);
    }
    const float h2 = a2 / (1.0f + __expf(-a2));   // silu

    float e = h2 * W3[lane];
    #pragma unroll
    for (int off = 32; off > 0; off >>= 1)
        e += __shfl_xor(e, off, 64);
    if (lane == 0) ered[w] = e;
    __syncthreads();

    if (tid < 64) {   // first wave: reduce 8 wave partials, store block partial
        float acc = (lane < WPB) ? ered[lane] : 0.0f;
        acc += __shfl_xor(acc, 4, 64);
        acc += __shfl_xor(acc, 2, 64);
        acc += __shfl_xor(acc, 1, 64);
        if (lane == 0) partial[blockIdx.x] = acc;
    }
}

// ---- node 4: reduce NBLOCKS partials -> out ----
__global__ __launch_bounds__(NTHREADS) void finish_kernel(
    const float* __restrict__ partial, const float* __restrict__ b3,
    float* __restrict__ out) {
    __shared__ float s[WPB];
    const int tid = threadIdx.x, lane = tid & 63, w = tid >> 6;
    float v = partial[tid];
    #pragma unroll
    for (int off = 32; off > 0; off >>= 1)
        v += __shfl_xor(v, off, 64);
    if (lane == 0) s[w] = v;
    __syncthreads();
    if (tid == 0) {
        float tot = 0.0f;
        #pragma unroll
        for (int i = 0; i < WPB; ++i) tot += s[i];
        out[0] = tot + (float)N_ATOMS * b3[0];
    }
}

extern "C" void kernel_launch(void* const* d_in, const int* in_sizes, int n_in,
                              void* d_out, int out_size, void* d_ws, size_t ws_size,
                              hipStream_t stream) {
    const float* pos = (const float*)d_in[0];
    const float* W1  = (const float*)d_in[1];
    const float* b1  = (const float*)d_in[2];
    const float* W2  = (const float*)d_in[3];
    const float* b2  = (const float*)d_in[4];
    const float* W3  = (const float*)d_in[5];
    const float* b3  = (const float*)d_in[6];
    float* out = (float*)d_out;

    // ws carve: count (55 KB) | cellAtoms (21.2 MB, 64KB-aligned) | partial
    int*    count     = (int*)d_ws;
    float4* cellAtoms = (float4*)((char*)d_ws + 65536);
    float*  partial   = (float*)((char*)d_ws + 65536 + (size_t)NCELL * CCAP * sizeof(float4));

    zero_counts<<<(NCELL + 255) / 256, 256, 0, stream>>>(count);
    bin_kernel<<<(N_ATOMS + 255) / 256, 256, 0, stream>>>(pos, count, cellAtoms);
    fused_sr_kernel<<<NBLOCKS, NTHREADS, 0, stream>>>(pos, count, cellAtoms,
                                                      W1, b1, W2, b2, W3, partial);
    finish_kernel<<<1, NTHREADS, 0, stream>>>(partial, b3, out);
}